// Round 5
// baseline (4530.136 us; speedup 1.0000x reference)
//
#include <hip/hip_runtime.h>

#define BATCH 512
#define SEQL  512
#define NIN   128
#define NH    512
#define NOUT  128
#define PRED  32
#define NSTEP (SEQL + PRED)

#define G_B 8
#define G_H 16
#define BT  64
#define UW  32              // hidden units per WG
#define NWG (G_B * G_H)     // 128
#define NTHREADS 256

#define OFF_WIH  49152      // shorts: Whh 96*512
#define OFF_WOUT 61440      // shorts: + Wih 96*128

typedef short bf16x8 __attribute__((ext_vector_type(8)));
typedef float f32x4 __attribute__((ext_vector_type(4)));
typedef unsigned int u32x4 __attribute__((ext_vector_type(4)));

#define MFMA __builtin_amdgcn_mfma_f32_16x16x32_bf16

__device__ __forceinline__ unsigned short f2bf(float f) {
    unsigned int u = __float_as_uint(f);
    u = (u + 0x7fffu + ((u >> 16) & 1u)) >> 16;   // RTNE
    return (unsigned short)u;
}
__device__ __forceinline__ float sigm(float x) {
    x = fminf(fmaxf(x, -30.f), 30.f);
    return 1.f / (1.f + __expf(-x));
}
__device__ __forceinline__ float tanh_f(float x) {
    x = fminf(fmaxf(x, -15.f), 15.f);
    float e = __expf(2.f * x);
    return (e - 1.f) / (e + 1.f);
}

// Zero h0 and the flag words with sc1 stores (land at the chip-coherent MALL
// point where the main kernel's sc1 loads read).
__global__ __launch_bounds__(256) void zero_kernel(unsigned short* hbuf, int* cnt)
{
    const int tid = threadIdx.x, wg = blockIdx.x;
    u32x4 z = {0, 0, 0, 0};
    char* base = (char*)hbuf + ((wg * 256 + tid) * 32);   // 64*256*32B = 512 KiB
    asm volatile("global_store_dwordx4 %0, %1, off sc1" :: "v"(base), "v"(z) : "memory");
    asm volatile("global_store_dwordx4 %0, %1, off offset:16 sc1" :: "v"(base), "v"(z) : "memory");
    if (wg == 0) {
        int zz = 0;
        asm volatile("global_store_dword %0, %1, off sc1" :: "v"(cnt + tid), "v"(zz) : "memory");
    }
}

// Persistent GRU kernel.
// WG (bg, hs): batch rows [bg*64, +64), hidden units [hs*32, +32).
// Sync (placement-independent, fence-free, ZERO cache maintenance, ZERO RMW):
//   h data  : sc1 stores/loads (complete at chip-coherent MALL point)
//   barrier : per-WG flag word = step count; producers do sc1 stores after
//             vmcnt(0)-draining h; consumers poll 16 flags with plain sc1
//             dwordx4 loads (concurrent, no atomic serialization).
// LDS 128 KiB: Whh[96][512] @0, Wih[96][128] @49152, Wout[8][512] @61440.
// Rows r: gate = r>>5, unit = hs*32 + (r&31). XOR swizzle (idx ^= (r&7)<<3).
__global__ __launch_bounds__(NTHREADS, 1) void gru_kernel(
    const float* __restrict__ z_seq, const float* __restrict__ W_ih,
    const float* __restrict__ W_hh, const float* __restrict__ b_ih,
    const float* __restrict__ b_hh, const float* __restrict__ W_out,
    const float* __restrict__ b_out, float* __restrict__ out,
    unsigned short* __restrict__ hbuf, int* __restrict__ cnt)
{
    __shared__ unsigned short s_w[65536];   // 128 KiB
    const int tid = threadIdx.x;
    const int wg  = blockIdx.x;
    const int bg  = wg & 7;
    const int hs  = wg >> 3;

    // ---- stage weight slices (fp32 global -> bf16 LDS, swizzled) ----
    for (int i = tid; i < 96 * 512; i += NTHREADS) {
        int r = i >> 9, k = i & 511;
        int grow = ((r >> 5) << 9) + hs * UW + (r & 31);   // gate*512 + unit
        s_w[(r << 9) + (k ^ ((r & 7) << 3))] = f2bf(W_hh[grow * 512 + k]);
    }
    for (int i = tid; i < 96 * 128; i += NTHREADS) {
        int r = i >> 7, k = i & 127;
        int grow = ((r >> 5) << 9) + hs * UW + (r & 31);
        s_w[OFF_WIH + (r << 7) + (k ^ ((r & 7) << 3))] = f2bf(W_ih[grow * 128 + k]);
    }
    for (int i = tid; i < 8 * 512; i += NTHREADS) {
        int r = i >> 9, k = i & 511;
        s_w[OFF_WOUT + (r << 9) + (k ^ ((r & 7) << 3))] = f2bf(W_out[(hs * 8 + r) * 512 + k]);
    }
    __syncthreads();

    const int lane = tid & 63;
    const int wave = tid >> 6;
    const int li   = lane & 15;       // MFMA row-of-A / col-of-B / col-of-C
    const int kq   = lane >> 4;       // k-chunk selector
    const int swz  = (li & 7) << 3;
    const int swzO = (li & 7) << 3;   // Wout: 8 real rows, cols duplicated x2
    const int jg0  = hs * UW + li;    // unit tile 0
    const int jg1  = jg0 + 16;        // unit tile 1

    const float bihr0 = b_ih[jg0], bihz0 = b_ih[NH + jg0], bihn0 = b_ih[2 * NH + jg0];
    const float bihr1 = b_ih[jg1], bihz1 = b_ih[NH + jg1], bihn1 = b_ih[2 * NH + jg1];
    const float bhhr0 = b_hh[jg0], bhhz0 = b_hh[NH + jg0], bhhn0 = b_hh[2 * NH + jg0];
    const float bhhr1 = b_hh[jg1], bhhz1 = b_hh[NH + jg1], bhhn1 = b_hh[2 * NH + jg1];
    const float bo    = b_out[hs * 8 + (li & 7)];

    const int aRow = bg * BT + wave * 16 + li;        // batch row for A frags
    const int cRow = bg * BT + wave * 16 + kq * 4;    // C rows (+q)
    float hreg[8] = {0,0,0,0,0,0,0,0};                // fp32 h state (2 tiles x 4)

    const unsigned short* wR0 = &s_w[(li) << 9];
    const unsigned short* wR1 = &s_w[(li + 16) << 9];
    const unsigned short* wZ0 = &s_w[(32 + li) << 9];
    const unsigned short* wZ1 = &s_w[(48 + li) << 9];
    const unsigned short* wN0 = &s_w[(64 + li) << 9];
    const unsigned short* wN1 = &s_w[(80 + li) << 9];
    const unsigned short* iR0 = &s_w[OFF_WIH + ((li) << 7)];
    const unsigned short* iR1 = &s_w[OFF_WIH + ((li + 16) << 7)];
    const unsigned short* iZ0 = &s_w[OFF_WIH + ((32 + li) << 7)];
    const unsigned short* iZ1 = &s_w[OFF_WIH + ((48 + li) << 7)];
    const unsigned short* iN0 = &s_w[OFF_WIH + ((64 + li) << 7)];
    const unsigned short* iN1 = &s_w[OFF_WIH + ((80 + li) << 7)];
    const unsigned short* oB  = &s_w[OFF_WOUT + ((li & 7) << 9)];

    int* flags  = cnt + bg * 32;          // 16 flag words per group, 128B apart
    int* myFlag = flags + hs;
    int  dead   = 0;

    for (int t = 0; t <= NSTEP; ++t) {
        const unsigned short* hin  = hbuf + (t & 1) * (BATCH * NH);
        unsigned short*       hout = hbuf + ((t & 1) ^ 1) * (BATCH * NH);

        // prefetch z_t (encode only); plain cached loads (read-only data)
        float4 zv0[4], zv1[4];
        if (t < SEQL) {
            const float* zrow = z_seq + ((long)aRow * SEQL + t) * NIN + kq * 8;
#pragma unroll
            for (int ks = 0; ks < 4; ++ks) {
                zv0[ks] = *(const float4*)(zrow + ks * 32);
                zv1[ks] = *(const float4*)(zrow + ks * 32 + 4);
            }
        }

        // A fragments: sc1 = agent-scope load from the MALL coherence point
        const unsigned short* hrow = hin + aRow * NH + kq * 8;
        bf16x8 a[16];
#pragma unroll
        for (int ks = 0; ks < 16; ++ks)
            asm volatile("global_load_dwordx4 %0, %1, off offset:%2 sc1"
                         : "=v"(a[ks]) : "v"(hrow), "i"(ks * 64) : "memory");
        asm volatile("s_waitcnt vmcnt(0)" ::: "memory");
        __builtin_amdgcn_sched_barrier(0);

        // decode: a[] holds h_t; y_td needs h_{SEQL+1+td} -> emit at t=SEQL+1+td
        if (t > SEQL) {
            int td = t - SEQL - 1;
            f32x4 y4 = {0, 0, 0, 0};
#pragma unroll
            for (int ks = 0; ks < 16; ++ks) {
                int so = (ks * 32 + kq * 8) ^ swzO;
                y4 = MFMA(a[ks], *(const bf16x8*)(oB + so), y4, 0, 0, 0);
            }
            if (li < 8) {
#pragma unroll
                for (int q = 0; q < 4; ++q)
                    out[((long)(cRow + q) * PRED + td) * NOUT + hs * 8 + li] = y4[q] + bo;
            }
        }
        if (t == NSTEP) break;

        f32x4 hr0 = {0,0,0,0}, hz0 = {0,0,0,0}, hn0 = {0,0,0,0};
        f32x4 hr1 = {0,0,0,0}, hz1 = {0,0,0,0}, hn1 = {0,0,0,0};
#pragma unroll
        for (int ks = 0; ks < 16; ++ks) {
            int so = (ks * 32 + kq * 8) ^ swz;
            hr0 = MFMA(a[ks], *(const bf16x8*)(wR0 + so), hr0, 0, 0, 0);
            hr1 = MFMA(a[ks], *(const bf16x8*)(wR1 + so), hr1, 0, 0, 0);
            hz0 = MFMA(a[ks], *(const bf16x8*)(wZ0 + so), hz0, 0, 0, 0);
            hz1 = MFMA(a[ks], *(const bf16x8*)(wZ1 + so), hz1, 0, 0, 0);
            hn0 = MFMA(a[ks], *(const bf16x8*)(wN0 + so), hn0, 0, 0, 0);
            hn1 = MFMA(a[ks], *(const bf16x8*)(wN1 + so), hn1, 0, 0, 0);
        }

        f32x4 ir0 = {0,0,0,0}, iz0 = {0,0,0,0}, in0 = {0,0,0,0};
        f32x4 ir1 = {0,0,0,0}, iz1 = {0,0,0,0}, in1 = {0,0,0,0};
        if (t < SEQL) {
#pragma unroll
            for (int ks = 0; ks < 4; ++ks) {
                union { bf16x8 v; unsigned short u[8]; } az;
                az.u[0] = f2bf(zv0[ks].x); az.u[1] = f2bf(zv0[ks].y);
                az.u[2] = f2bf(zv0[ks].z); az.u[3] = f2bf(zv0[ks].w);
                az.u[4] = f2bf(zv1[ks].x); az.u[5] = f2bf(zv1[ks].y);
                az.u[6] = f2bf(zv1[ks].z); az.u[7] = f2bf(zv1[ks].w);
                int so = (ks * 32 + kq * 8) ^ swz;
                ir0 = MFMA(az.v, *(const bf16x8*)(iR0 + so), ir0, 0, 0, 0);
                ir1 = MFMA(az.v, *(const bf16x8*)(iR1 + so), ir1, 0, 0, 0);
                iz0 = MFMA(az.v, *(const bf16x8*)(iZ0 + so), iz0, 0, 0, 0);
                iz1 = MFMA(az.v, *(const bf16x8*)(iZ1 + so), iz1, 0, 0, 0);
                in0 = MFMA(az.v, *(const bf16x8*)(iN0 + so), in0, 0, 0, 0);
                in1 = MFMA(az.v, *(const bf16x8*)(iN1 + so), in1, 0, 0, 0);
            }
        }

        // gate math; h stores go sc1 (straight to the MALL coherence point)
#pragma unroll
        for (int q = 0; q < 4; ++q) {
            float r0 = sigm(bihr0 + ir0[q] + bhhr0 + hr0[q]);
            float z0 = sigm(bihz0 + iz0[q] + bhhz0 + hz0[q]);
            float n0 = tanh_f(bihn0 + in0[q] + r0 * (bhhn0 + hn0[q]));
            float h0 = (1.f - z0) * n0 + z0 * hreg[q];
            hreg[q] = h0;
            unsigned short* hp0 = hout + (cRow + q) * NH + jg0;
            int hb0 = (int)f2bf(h0);
            asm volatile("global_store_short %0, %1, off sc1"
                         :: "v"(hp0), "v"(hb0) : "memory");

            float r1 = sigm(bihr1 + ir1[q] + bhhr1 + hr1[q]);
            float z1 = sigm(bihz1 + iz1[q] + bhhz1 + hz1[q]);
            float n1 = tanh_f(bihn1 + in1[q] + r1 * (bhhn1 + hn1[q]));
            float h1 = (1.f - z1) * n1 + z1 * hreg[4 + q];
            hreg[4 + q] = h1;
            unsigned short* hp1 = hout + (cRow + q) * NH + jg1;
            int hb1 = (int)f2bf(h1);
            asm volatile("global_store_short %0, %1, off sc1"
                         :: "v"(hp1), "v"(hb1) : "memory");
        }

        // ---- flag-vector barrier, one per step, NO atomics ----
        // sc1 h-stores drain (vmcnt retires at coherence point) -> WG sync ->
        // tid0 sc1-stores flag = t+1 -> every wave's lane 0 polls the 16
        // group flags with plain sc1 dwordx4 loads until min >= t+1.
        asm volatile("s_waitcnt vmcnt(0)" ::: "memory");
        __syncthreads();
        if (tid == 0) {
            int v = t + 1;
            asm volatile("global_store_dword %0, %1, off sc1"
                         :: "v"(myFlag), "v"(v) : "memory");
        }
        const int target = t + 1;
        int bail = 0;
        if (!dead && lane == 0) {
            int patience = 2000000;
            for (;;) {
                int4 f0, f1, f2, f3;
                asm volatile(
                    "global_load_dwordx4 %0, %4, off sc1\n\t"
                    "global_load_dwordx4 %1, %4, off offset:16 sc1\n\t"
                    "global_load_dwordx4 %2, %4, off offset:32 sc1\n\t"
                    "global_load_dwordx4 %3, %4, off offset:48 sc1\n\t"
                    "s_waitcnt vmcnt(0)"
                    : "=v"(f0), "=v"(f1), "=v"(f2), "=v"(f3)
                    : "v"(flags) : "memory");
                int m = min(min(min(f0.x, f0.y), min(f0.z, f0.w)),
                        min(min(min(f1.x, f1.y), min(f1.z, f1.w)),
                        min(min(min(f2.x, f2.y), min(f2.z, f2.w)),
                            min(min(f3.x, f3.y), min(f3.z, f3.w)))));
                if (m >= target) break;
                __builtin_amdgcn_s_sleep(2);
                if (--patience == 0) { bail = 1; break; }
            }
        }
        dead |= __builtin_amdgcn_readfirstlane(bail);
        __builtin_amdgcn_sched_barrier(0);
    }
}

extern "C" void kernel_launch(void* const* d_in, const int* in_sizes, int n_in,
                              void* d_out, int out_size, void* d_ws, size_t ws_size,
                              hipStream_t stream)
{
    const float* z_seq = (const float*)d_in[0];
    const float* W_ih  = (const float*)d_in[1];
    const float* W_hh  = (const float*)d_in[2];
    const float* b_ih  = (const float*)d_in[3];
    const float* b_hh  = (const float*)d_in[4];
    const float* W_out = (const float*)d_in[5];
    const float* b_out = (const float*)d_in[6];
    float* out = (float*)d_out;

    unsigned short* hbuf = (unsigned short*)d_ws;                   // 2 x [512][512] bf16
    int* cnt = (int*)((char*)d_ws + (size_t)2 * BATCH * NH * 2);    // flag words

    zero_kernel<<<dim3(64), dim3(256), 0, stream>>>(hbuf, cnt);
    gru_kernel<<<dim3(NWG), dim3(NTHREADS), 0, stream>>>(
        z_seq, W_ih, W_hh, b_ih, b_hh, W_out, b_out, out, hbuf, cnt);
}

// Round 7
// 2818.145 us; speedup vs baseline: 1.6075x; 1.6075x over previous
//
#include <hip/hip_runtime.h>

#define BATCH 512
#define SEQL  512
#define NIN   128
#define NH    512
#define NOUT  128
#define PRED  32
#define NSTEP (SEQL + PRED)

#define G_B 8
#define G_H 32
#define BT  64
#define NWG (G_B * G_H)
#define NTHREADS 256

// LDS layout (shorts). Weights stored in MFMA-FRAGMENT order:
// frag (g, ks) base = (g*16+ks)*512 + lane*8  -> ds_read_b128 is perfectly
// linear per instruction (lane*16B), ZERO bank conflicts, no index math.
#define OFF_WIH  24576      // Whh frags: 3 gates * 16 ks * 64 lanes * 8
#define OFF_WOUT 30720      // Wih frags: 3 gates *  4 ks * 64 lanes * 8
#define OFF_TR   38912      // Wout frags: 16 ks * 64 lanes * 8
#define LDS_SH   40448      // + 4 waves * 384 transpose scratch

typedef short bf16x8 __attribute__((ext_vector_type(8)));
typedef float f32x4 __attribute__((ext_vector_type(4)));
typedef unsigned int u32x4 __attribute__((ext_vector_type(4)));

#define MFMA __builtin_amdgcn_mfma_f32_16x16x32_bf16

__device__ __forceinline__ unsigned short f2bf(float f) {
    unsigned int u = __float_as_uint(f);
    u = (u + 0x7fffu + ((u >> 16) & 1u)) >> 16;   // RTNE
    return (unsigned short)u;
}
__device__ __forceinline__ float sigm(float x) {
    x = fminf(fmaxf(x, -30.f), 30.f);
    return 1.f / (1.f + __expf(-x));
}
__device__ __forceinline__ float tanh_f(float x) {
    x = fminf(fmaxf(x, -15.f), 15.f);
    float e = __expf(2.f * x);
    return (e - 1.f) / (e + 1.f);
}

// Zero h0 and the flag words with sc1 stores (land at the chip-coherent MALL
// point where the main kernel's sc1 loads read).
__global__ __launch_bounds__(256) void zero_kernel(unsigned short* hbuf, int* cnt)
{
    const int tid = threadIdx.x, wg = blockIdx.x;
    u32x4 z = {0, 0, 0, 0};
    char* base = (char*)hbuf + ((wg * 256 + tid) * 32);   // 64*256*32B = 512 KiB
    asm volatile("global_store_dwordx4 %0, %1, off sc1" :: "v"(base), "v"(z) : "memory");
    asm volatile("global_store_dwordx4 %0, %1, off offset:16 sc1" :: "v"(base), "v"(z) : "memory");
    if (wg == 0) {
        int zz = 0;
        asm volatile("global_store_dword %0, %1, off sc1" :: "v"(cnt + tid), "v"(zz) : "memory");
        asm volatile("global_store_dword %0, %1, off sc1" :: "v"(cnt + 256 + tid), "v"(zz) : "memory");
    }
}

// Persistent GRU kernel. WG (bg, hs): batch rows [bg*64,+64), units [hs*16,+16).
// Sync: sc1 data stores/loads (chip-coherent MALL point) + per-WG flag words
// polled with plain sc1 loads (no RMW, no cache maintenance).
// h stores coalesced via per-wave LDS transpose -> global_store_dwordx4 sc1.
// Input-side (z) MFMA for step t+1 computed in the barrier-wait shadow.
__global__ __launch_bounds__(NTHREADS, 1) void gru_kernel(
    const float* __restrict__ z_seq, const float* __restrict__ W_ih,
    const float* __restrict__ W_hh, const float* __restrict__ b_ih,
    const float* __restrict__ b_hh, const float* __restrict__ W_out,
    const float* __restrict__ b_out, float* __restrict__ out,
    unsigned short* __restrict__ hbuf, int* __restrict__ cnt)
{
    __shared__ unsigned short s_w[LDS_SH];
    const int tid = threadIdx.x;
    const int wg  = blockIdx.x;
    const int bg  = wg & 7;
    const int hs  = wg >> 3;

    // ---- stage weights in fragment-linear order (fp32 -> bf16) ----
    // Whh: i = g*8192 + ks*512 + lane*8 + e ; value = Whh[g*512+unit][k]
    for (int i = tid; i < 24576; i += NTHREADS) {
        int e = i & 7, ln = (i >> 3) & 63, ks = (i >> 9) & 15, g = i >> 13;
        int unit = hs * 16 + (ln & 15);
        int k = ks * 32 + (ln >> 4) * 8 + e;
        s_w[i] = f2bf(W_hh[(g * 512 + unit) * 512 + k]);
    }
    for (int i = tid; i < 6144; i += NTHREADS) {
        int e = i & 7, ln = (i >> 3) & 63, ks = (i >> 9) & 3, g = i >> 11;
        int unit = hs * 16 + (ln & 15);
        int k = ks * 32 + (ln >> 4) * 8 + e;
        s_w[OFF_WIH + i] = f2bf(W_ih[(g * 512 + unit) * 128 + k]);
    }
    for (int i = tid; i < 8192; i += NTHREADS) {
        int e = i & 7, ln = (i >> 3) & 63, ks = i >> 9;
        int ocol = hs * 4 + (ln & 3);           // cols duplicated x4
        int k = ks * 32 + (ln >> 4) * 8 + e;
        s_w[OFF_WOUT + i] = f2bf(W_out[ocol * 512 + k]);
    }
    __syncthreads();

    const int lane = tid & 63;
    const int wave = tid >> 6;
    const int li   = lane & 15;       // MFMA row-of-A / col-of-B / col-of-C
    const int kq   = lane >> 4;       // k-chunk selector
    const int jg   = hs * 16 + li;    // global hidden unit of this lane

    const float bihr = b_ih[jg], bihz = b_ih[NH + jg], bihn = b_ih[2 * NH + jg];
    const float bhhr = b_hh[jg], bhhz = b_hh[NH + jg], bhhn = b_hh[2 * NH + jg];
    const float bo   = b_out[hs * 4 + (li & 3)];

    const int aRow = bg * BT + wave * 16 + li;        // batch row for A frags
    const int cRow = bg * BT + wave * 16 + kq * 4;    // C rows (+q)
    float hreg[4] = {0.f, 0.f, 0.f, 0.f};             // fp32 h state in regs

    const unsigned short* fb = s_w + lane * 8;            // per-lane frag base
    unsigned short* tr = s_w + OFF_TR + wave * 384;       // transpose scratch

    int* gflags = cnt + bg * 64;          // 32 contiguous flag ints per group
    int* myFlag = gflags + hs;
    int  dead   = 0;

    // ---- prologue: input-side pre-activations for t = 0 ----
    f32x4 ir = {0,0,0,0}, iz = {0,0,0,0}, in = {0,0,0,0};
    {
        const float* zrow = z_seq + ((long)aRow * SEQL + 0) * NIN + kq * 8;
#pragma unroll
        for (int ks = 0; ks < 4; ++ks) {
            float4 z0 = *(const float4*)(zrow + ks * 32);
            float4 z1 = *(const float4*)(zrow + ks * 32 + 4);
            union { bf16x8 v; unsigned short u[8]; } az;
            az.u[0] = f2bf(z0.x); az.u[1] = f2bf(z0.y);
            az.u[2] = f2bf(z0.z); az.u[3] = f2bf(z0.w);
            az.u[4] = f2bf(z1.x); az.u[5] = f2bf(z1.y);
            az.u[6] = f2bf(z1.z); az.u[7] = f2bf(z1.w);
            ir = MFMA(az.v, *(const bf16x8*)(fb + OFF_WIH + ks * 512), ir, 0, 0, 0);
            iz = MFMA(az.v, *(const bf16x8*)(fb + OFF_WIH + 2048 + ks * 512), iz, 0, 0, 0);
            in = MFMA(az.v, *(const bf16x8*)(fb + OFF_WIH + 4096 + ks * 512), in, 0, 0, 0);
        }
    }

    for (int t = 0; t <= NSTEP; ++t) {
        const unsigned short* hin  = hbuf + (t & 1) * (BATCH * NH);
        unsigned short*       hout = hbuf + ((t & 1) ^ 1) * (BATCH * NH);

        // A fragments: sc1 = agent-scope load from the MALL coherence point
        const unsigned short* hrow = hin + aRow * NH + kq * 8;
        bf16x8 a[16];
#pragma unroll
        for (int ks = 0; ks < 16; ++ks)
            asm volatile("global_load_dwordx4 %0, %1, off offset:%2 sc1"
                         : "=v"(a[ks]) : "v"(hrow), "i"(ks * 64) : "memory");
        asm volatile("s_waitcnt vmcnt(0)" ::: "memory");
        __builtin_amdgcn_sched_barrier(0);

        // decode: a[] holds h_t; y_td needs h_{SEQL+1+td} -> emit at t=SEQL+1+td
        if (t > SEQL) {
            int td = t - SEQL - 1;
            f32x4 y4 = {0, 0, 0, 0};
#pragma unroll
            for (int ks = 0; ks < 16; ++ks)
                y4 = MFMA(a[ks], *(const bf16x8*)(fb + OFF_WOUT + ks * 512), y4, 0, 0, 0);
            if (li < 4) {
#pragma unroll
                for (int q = 0; q < 4; ++q)
                    out[((long)(cRow + q) * PRED + td) * NOUT + hs * 4 + li] = y4[q] + bo;
            }
        }
        if (t == NSTEP) break;

        // hidden-side MFMA: fragment-linear B reads (zero bank conflicts)
        f32x4 hr = {0,0,0,0}, hz = {0,0,0,0}, hn = {0,0,0,0};
#pragma unroll
        for (int ks = 0; ks < 16; ++ks) {
            hr = MFMA(a[ks], *(const bf16x8*)(fb + ks * 512), hr, 0, 0, 0);
            hz = MFMA(a[ks], *(const bf16x8*)(fb + 8192 + ks * 512), hz, 0, 0, 0);
            hn = MFMA(a[ks], *(const bf16x8*)(fb + 16384 + ks * 512), hn, 0, 0, 0);
        }

        // gate math -> bf16 into per-wave LDS transpose tile (rows stride 24)
#pragma unroll
        for (int q = 0; q < 4; ++q) {
            float r  = sigm(bihr + ir[q] + bhhr + hr[q]);
            float zz = sigm(bihz + iz[q] + bhhz + hz[q]);
            float nn = tanh_f(bihn + in[q] + r * (bhhn + hn[q]));
            float hq = (1.f - zz) * nn + zz * hreg[q];
            hreg[q]  = hq;
            tr[(kq * 4 + q) * 24 + li] = f2bf(hq);
        }
        asm volatile("s_waitcnt lgkmcnt(0)" ::: "memory");
        __builtin_amdgcn_sched_barrier(0);

        // coalesced h store: 32 lanes x dwordx4 sc1 (16 rows x 2 chunks)
        if (lane < 32) {
            bf16x8 hv = *(const bf16x8*)(tr + (lane >> 1) * 24 + (lane & 1) * 8);
            int grow = bg * BT + wave * 16 + (lane >> 1);
            unsigned short* hp = hout + grow * NH + hs * 16 + (lane & 1) * 8;
            asm volatile("global_store_dwordx4 %0, %1, off sc1"
                         :: "v"(hp), "v"(hv) : "memory");
        }
        asm volatile("s_waitcnt vmcnt(0)" ::: "memory");
        __syncthreads();
        if (tid == 0) {
            int v = t + 1;
            asm volatile("global_store_dword %0, %1, off sc1"
                         :: "v"(myFlag), "v"(v) : "memory");
        }

        // ---- barrier shadow: input-side pre-activations for t+1 ----
        f32x4 nir = {0,0,0,0}, niz = {0,0,0,0}, nin = {0,0,0,0};
        if (t + 1 < SEQL) {
            const float* zrow = z_seq + ((long)aRow * SEQL + (t + 1)) * NIN + kq * 8;
#pragma unroll
            for (int ks = 0; ks < 4; ++ks) {
                float4 z0 = *(const float4*)(zrow + ks * 32);
                float4 z1 = *(const float4*)(zrow + ks * 32 + 4);
                union { bf16x8 v; unsigned short u[8]; } az;
                az.u[0] = f2bf(z0.x); az.u[1] = f2bf(z0.y);
                az.u[2] = f2bf(z0.z); az.u[3] = f2bf(z0.w);
                az.u[4] = f2bf(z1.x); az.u[5] = f2bf(z1.y);
                az.u[6] = f2bf(z1.z); az.u[7] = f2bf(z1.w);
                nir = MFMA(az.v, *(const bf16x8*)(fb + OFF_WIH + ks * 512), nir, 0, 0, 0);
                niz = MFMA(az.v, *(const bf16x8*)(fb + OFF_WIH + 2048 + ks * 512), niz, 0, 0, 0);
                nin = MFMA(az.v, *(const bf16x8*)(fb + OFF_WIH + 4096 + ks * 512), nin, 0, 0, 0);
            }
        }

        // ---- flag-vector poll: plain sc1 loads of 32 ints, min >= t+1 ----
        // "=&v" EARLY-CLOBBER is required: outputs are written by the first
        // loads while %8 (the pointer) is still read by later loads — without
        // & the allocator may overlap them (round 6's memory-fault crash).
        const int target = t + 1;
        int bail = 0;
        if (!dead && lane == 0) {
            int patience = 4000000;
            for (;;) {
                int4 f0, f1, f2, f3, f4, f5, f6, f7;
                asm volatile(
                    "global_load_dwordx4 %0, %8, off sc1\n\t"
                    "global_load_dwordx4 %1, %8, off offset:16 sc1\n\t"
                    "global_load_dwordx4 %2, %8, off offset:32 sc1\n\t"
                    "global_load_dwordx4 %3, %8, off offset:48 sc1\n\t"
                    "global_load_dwordx4 %4, %8, off offset:64 sc1\n\t"
                    "global_load_dwordx4 %5, %8, off offset:80 sc1\n\t"
                    "global_load_dwordx4 %6, %8, off offset:96 sc1\n\t"
                    "global_load_dwordx4 %7, %8, off offset:112 sc1\n\t"
                    "s_waitcnt vmcnt(0)"
                    : "=&v"(f0), "=&v"(f1), "=&v"(f2), "=&v"(f3),
                      "=&v"(f4), "=&v"(f5), "=&v"(f6), "=&v"(f7)
                    : "v"(gflags) : "memory");
                int m0 = min(min(min(f0.x, f0.y), min(f0.z, f0.w)),
                             min(min(f1.x, f1.y), min(f1.z, f1.w)));
                int m1 = min(min(min(f2.x, f2.y), min(f2.z, f2.w)),
                             min(min(f3.x, f3.y), min(f3.z, f3.w)));
                int m2 = min(min(min(f4.x, f4.y), min(f4.z, f4.w)),
                             min(min(f5.x, f5.y), min(f5.z, f5.w)));
                int m3 = min(min(min(f6.x, f6.y), min(f6.z, f6.w)),
                             min(min(f7.x, f7.y), min(f7.z, f7.w)));
                if (min(min(m0, m1), min(m2, m3)) >= target) break;
                if (--patience == 0) { bail = 1; break; }
            }
        }
        dead |= __builtin_amdgcn_readfirstlane(bail);
        __builtin_amdgcn_sched_barrier(0);

        ir = nir; iz = niz; in = nin;
    }
}

extern "C" void kernel_launch(void* const* d_in, const int* in_sizes, int n_in,
                              void* d_out, int out_size, void* d_ws, size_t ws_size,
                              hipStream_t stream)
{
    const float* z_seq = (const float*)d_in[0];
    const float* W_ih  = (const float*)d_in[1];
    const float* W_hh  = (const float*)d_in[2];
    const float* b_ih  = (const float*)d_in[3];
    const float* b_hh  = (const float*)d_in[4];
    const float* W_out = (const float*)d_in[5];
    const float* b_out = (const float*)d_in[6];
    float* out = (float*)d_out;

    unsigned short* hbuf = (unsigned short*)d_ws;                   // 2 x [512][512] bf16
    int* cnt = (int*)((char*)d_ws + (size_t)2 * BATCH * NH * 2);    // flag words

    zero_kernel<<<dim3(64), dim3(256), 0, stream>>>(hbuf, cnt);
    gru_kernel<<<dim3(NWG), dim3(NTHREADS), 0, stream>>>(
        z_seq, W_ih, W_hh, b_ih, b_hh, W_out, b_out, out, hbuf, cnt);
}